// Round 1
// baseline (226.213 us; speedup 1.0000x reference)
//
#include <hip/hip_runtime.h>
#include <math.h>

#define SEQL 256
#define DST 16

struct Params {
    const float* norm_b;
    const float* in_proj_w;
    const float* conv_w[3];
    const float* conv_b[3];
    const float* xproj_w[3];
    const float* dtproj_w[3];
    const float* dtproj_b[3];
    const float* A_log[3];
    const float* Dskip[3];
    const float* out_proj_w;
    const float* w1; const float* b1;
    const float* w2; const float* b2;
    const float* w3; const float* b3;
    float* row;   // d_ws: 100-float result row
};

__device__ __forceinline__ float silu_f(float x)     { return x / (1.0f + expf(-x)); }
__device__ __forceinline__ float softplus_f(float x) { return x > 0.f ? x + log1pf(expf(-x)) : log1pf(expf(x)); }
__device__ __forceinline__ float elu_f(float x)      { return x > 0.f ? x : expm1f(x); }

// One workgroup computes the entire batch-constant pipeline and writes the
// 100-float output row to p.row.
__global__ __launch_bounds__(512) void compute_row(Params p) {
    __shared__ float xs[3][2][SEQL];   // post-conv silu'd x, per direction
    __shared__ float dl[3][2][SEQL];   // delta, per direction
    __shared__ float od[3][2][SEQL];   // per-direction output, already in FINAL l-index space
    __shared__ float yrow[SEQL];
    __shared__ float h1s[512];
    __shared__ float h2s[256];

    const int tid = threadIdx.x;

    // hn == norm_b[0] exactly (LayerNorm over a singleton axis): xz constant.
    const float nb0 = p.norm_b[0];
    const float c0  = nb0 * p.in_proj_w[0];   // x channel 0
    const float c1  = nb0 * p.in_proj_w[1];   // x channel 1
    const float cz0 = nb0 * p.in_proj_w[2];   // z channel 0
    const float cz1 = nb0 * p.in_proj_w[3];   // z channel 1

    // Phase A: per-position conv + silu + delta (parallel over l)
    if (tid < SEQL) {
        const int l = tid;
        for (int dir = 0; dir < 3; ++dir) {
            const float* cw  = p.conv_w[dir];
            const float* cb  = p.conv_b[dir];
            const float* xp  = p.xproj_w[dir];
            const float* dtw = p.dtproj_w[dir];
            const float* dtb = p.dtproj_b[dir];
            float xsv[2];
            for (int d = 0; d < 2; ++d) {
                float s = 0.f;                       // causal conv on a constant sequence
                for (int k = 0; k < 4; ++k)
                    if (l - 3 + k >= 0) s += cw[d * 4 + k];
                const float cd = (d == 0) ? c0 : c1;
                const float xc = cd * s + cb[d];
                xsv[d] = silu_f(xc);
                xs[dir][d][l] = xsv[d];
            }
            const float xd0 = xp[0] * xsv[0] + xp[1] * xsv[1];   // xdbl row 0 (DT_RANK=1)
            for (int d = 0; d < 2; ++d)
                dl[dir][d][l] = softplus_f(dtw[d] * xd0 + dtb[d]);
        }
    }
    __syncthreads();

    // Phase B: selective scans. 96 threads = (dir 3) x (d 2) x (n 16).
    if (tid < 96) {
        const int dir = tid / 32;
        const int r   = tid % 32;
        const int d   = r / 16;
        const int n   = r % 16;
        const float* xp = p.xproj_w[dir];
        const float A   = -expf(p.A_log[dir][d * DST + n]);
        const float bx0 = xp[(1 + n) * 2 + 0],       bx1 = xp[(1 + n) * 2 + 1];
        const float cx0 = xp[(1 + DST + n) * 2 + 0], cx1 = xp[(1 + DST + n) * 2 + 1];
        const float Dsk = p.Dskip[dir][d];
        const float sz  = silu_f(d == 0 ? cz0 : cz1);
        float h = 0.f;
        for (int l = 0; l < SEQL; ++l) {
            const float x0 = xs[dir][0][l], x1 = xs[dir][1][l];
            const float u   = (d == 0) ? x0 : x1;
            const float dlt = dl[dir][d][l];
            const float Bn  = bx0 * x0 + bx1 * x1;
            const float Cn  = cx0 * x0 + cx1 * x1;
            h = expf(dlt * A) * h + (dlt * u) * Bn;
            float pv = h * Cn;
            pv += __shfl_xor(pv, 1);
            pv += __shfl_xor(pv, 2);
            pv += __shfl_xor(pv, 4);
            pv += __shfl_xor(pv, 8);
            if (n == 0) {
                const float y = pv + u * Dsk;
                // map raw scan position -> final sequence index
                int j;
                if      (dir == 0) j = l;                          // forward
                else if (dir == 1) j = SEQL - 1 - l;               // backward (flip)
                else               j = (l & 63) * 4 + (l >> 6);    // slice perm inverse
                od[dir][d][j] = y * sz;
            }
        }
    }
    __syncthreads();

    // Phase C: combine directions + out_proj -> yrow[256]
    if (tid < SEQL) {
        const float t0 = od[0][0][tid] + od[1][0][tid] + od[2][0][tid];
        const float t1 = od[0][1][tid] + od[1][1][tid] + od[2][1][tid];
        yrow[tid] = p.out_proj_w[0] * t0 + p.out_proj_w[1] * t1;
    }
    __syncthreads();

    // Phase D: MLP 256 -> 512 -> 256 -> 100
    {
        const int j = tid;                       // 0..511
        float acc = p.b1[j];
        const float* wr = p.w1 + j * 256;
        for (int l = 0; l < 256; ++l) acc += yrow[l] * wr[l];
        h1s[j] = elu_f(acc);
    }
    __syncthreads();
    if (tid < 256) {
        float acc = p.b2[tid];
        const float* wr = p.w2 + tid * 512;
        for (int k = 0; k < 512; ++k) acc += h1s[k] * wr[k];
        h2s[tid] = elu_f(acc);
    }
    __syncthreads();
    if (tid < 100) {
        float acc = p.b3[tid];
        const float* wr = p.w3 + tid * 256;
        for (int k = 0; k < 256; ++k) acc += h2s[k] * wr[k];
        p.row[tid] = acc;
    }
}

// Broadcast the 100-float row to all 8192 output rows.
// 100 floats = 25 float4 per row; rows are 400 B so float4 alignment holds.
__global__ __launch_bounds__(256) void bcast_row(const float4* __restrict__ row4,
                                                 float4* __restrict__ out4, int total4) {
    const int idx = blockIdx.x * blockDim.x + threadIdx.x;
    if (idx < total4) {
        const int c = idx % 25;
        out4[idx] = row4[c];
    }
}

extern "C" void kernel_launch(void* const* d_in, const int* in_sizes, int n_in,
                              void* d_out, int out_size, void* d_ws, size_t ws_size,
                              hipStream_t stream) {
    const float* const* in = (const float* const*)d_in;
    Params p;
    p.norm_b    = in[2];
    p.in_proj_w = in[3];
    for (int dir = 0; dir < 3; ++dir) {
        const int base = 4 + dir * 7;
        p.conv_w[dir]   = in[base + 0];
        p.conv_b[dir]   = in[base + 1];
        p.xproj_w[dir]  = in[base + 2];
        p.dtproj_w[dir] = in[base + 3];
        p.dtproj_b[dir] = in[base + 4];
        p.A_log[dir]    = in[base + 5];
        p.Dskip[dir]    = in[base + 6];
    }
    p.out_proj_w = in[25];
    p.w1 = in[26]; p.b1 = in[27];
    p.w2 = in[28]; p.b2 = in[29];
    p.w3 = in[30]; p.b3 = in[31];
    p.row = (float*)d_ws;

    compute_row<<<1, 512, 0, stream>>>(p);

    const int total4 = (8192 * 100) / 4;   // 204800
    bcast_row<<<(total4 + 255) / 256, 256, 0, stream>>>(
        (const float4*)d_ws, (float4*)d_out, total4);
}

// Round 2
// 156.065 us; speedup vs baseline: 1.4495x; 1.4495x over previous
//
#include <hip/hip_runtime.h>
#include <math.h>

#define SEQL 256

struct P1 {
    const float* norm_b;
    const float* in_proj_w;
    const float* conv_w[3];
    const float* conv_b[3];
    const float* xproj_w[3];
    const float* dtproj_w[3];
    const float* dtproj_b[3];
    const float* A_log[3];
    const float* Dskip[3];
    const float* out_proj_w;
    float* yrow;   // d_ws + 0 : 256 floats
};

__device__ __forceinline__ float silu_f(float x)     { return x / (1.0f + expf(-x)); }
__device__ __forceinline__ float softplus_f(float x) { return x > 0.f ? x + log1pf(expf(-x)) : log1pf(expf(x)); }
__device__ __forceinline__ float elu_f(float x)      { return x > 0.f ? x : expm1f(x); }

// ---------------------------------------------------------------------------
// K1: batch-constant mamba pipeline -> yrow[256] in d_ws.
// One block, 256 threads. Scan has NO in-loop shuffles: 48 threads run 2
// recurrences each, writing paired-n product sums to hc[l][q] (49-pad =>
// conflict-free on both the fixed-l write and the fixed-q gather).
// ---------------------------------------------------------------------------
__global__ __launch_bounds__(256) void k_row(P1 p) {
    __shared__ float xs[3][2][SEQL];   // post-conv silu'd x
    __shared__ float dl[3][2][SEQL];   // delta
    __shared__ float hc[SEQL][49];     // q = (dir*2+d)*8 + k, pair-summed over n

    const int tid = threadIdx.x;
    const float nb0 = p.norm_b[0];                 // LayerNorm over singleton axis == norm_b
    const float c0  = nb0 * p.in_proj_w[0];
    const float c1  = nb0 * p.in_proj_w[1];

    // Phase A: conv + silu + delta, parallel over l (l = tid)
    {
        const int l = tid;
        for (int dir = 0; dir < 3; ++dir) {
            const float* cw  = p.conv_w[dir];
            const float* cb  = p.conv_b[dir];
            const float* xp  = p.xproj_w[dir];
            const float* dtw = p.dtproj_w[dir];
            const float* dtb = p.dtproj_b[dir];
            float xsv[2];
            for (int d = 0; d < 2; ++d) {
                float s = 0.f;                       // causal conv of a constant sequence
                for (int k = 0; k < 4; ++k)
                    if (l - 3 + k >= 0) s += cw[d * 4 + k];
                const float xc = (d == 0 ? c0 : c1) * s + cb[d];
                xsv[d] = silu_f(xc);
                xs[dir][d][l] = xsv[d];
            }
            const float xd0 = xp[0] * xsv[0] + xp[1] * xsv[1];   // DT_RANK = 1
            dl[dir][0][l] = softplus_f(dtw[0] * xd0 + dtb[0]);
            dl[dir][1][l] = softplus_f(dtw[1] * xd0 + dtb[1]);
        }
    }
    __syncthreads();

    // Phase B: 48 threads x 2 recurrences. Dependent chain is just the fma;
    // exp/B/C are loop-independent and pipeline.
    if (tid < 48) {
        const int dir = tid / 16;
        const int r   = tid % 16;
        const int d   = r / 8;
        const int k   = r % 8;
        const int n0  = 2 * k, n1 = 2 * k + 1;
        const float* xp = p.xproj_w[dir];
        const float A0 = -expf(p.A_log[dir][d * 16 + n0]);
        const float A1 = -expf(p.A_log[dir][d * 16 + n1]);
        const float b00 = xp[(1 + n0) * 2],      b01 = xp[(1 + n0) * 2 + 1];
        const float b10 = xp[(1 + n1) * 2],      b11 = xp[(1 + n1) * 2 + 1];
        const float c00 = xp[(17 + n0) * 2],     c01 = xp[(17 + n0) * 2 + 1];
        const float c10 = xp[(17 + n1) * 2],     c11 = xp[(17 + n1) * 2 + 1];
        const int q = (dir * 2 + d) * 8 + k;
        float h0 = 0.f, h1 = 0.f;
        for (int l = 0; l < SEQL; ++l) {
            const float x0 = xs[dir][0][l], x1 = xs[dir][1][l];
            const float dlt = dl[dir][d][l];
            const float u   = (d == 0) ? x0 : x1;
            const float du  = dlt * u;
            h0 = expf(dlt * A0) * h0 + du * (b00 * x0 + b01 * x1);
            h1 = expf(dlt * A1) * h1 + du * (b10 * x0 + b11 * x1);
            hc[l][q] = h0 * (c00 * x0 + c01 * x1) + h1 * (c10 * x0 + c11 * x1);
        }
    }
    __syncthreads();

    // Phase C: reduce over n, apply Dskip/silu(z)/out_proj and the
    // per-direction l-permutations; t = final sequence index.
    {
        const int t = tid;
        const float opw0 = p.out_proj_w[0], opw1 = p.out_proj_w[1];
        const float sz0  = silu_f(nb0 * p.in_proj_w[2]);
        const float sz1  = silu_f(nb0 * p.in_proj_w[3]);
        float acc = 0.f;
        for (int dir = 0; dir < 3; ++dir) {
            int lv;
            if      (dir == 0) lv = t;                          // forward
            else if (dir == 1) lv = SEQL - 1 - t;               // backward
            else               lv = ((t & 3) << 6) + (t >> 2);  // slice perm inverse
            float s0 = 0.f, s1 = 0.f;
            for (int k = 0; k < 8; ++k) {
                s0 += hc[lv][dir * 16 + k];
                s1 += hc[lv][dir * 16 + 8 + k];
            }
            const float y0 = (s0 + xs[dir][0][lv] * p.Dskip[dir][0]) * sz0;
            const float y1 = (s1 + xs[dir][1][lv] * p.Dskip[dir][1]) * sz1;
            acc += opw0 * y0 + opw1 * y1;
        }
        p.yrow[t] = acc;
    }
}

// ---------------------------------------------------------------------------
// MLP: one block per output row, coalesced float4 loads + shuffle reduce.
// Weight fetch is distributed across hundreds of CUs (parallel cold miss).
// ---------------------------------------------------------------------------
__global__ __launch_bounds__(64) void k_mlp1(const float* __restrict__ w1, const float* __restrict__ b1,
                                             const float* __restrict__ yrow, float* __restrict__ h1) {
    const int j = blockIdx.x, t = threadIdx.x;       // 512 blocks x 64 lanes
    const float4 w = reinterpret_cast<const float4*>(w1)[j * 64 + t];
    const float4 y = reinterpret_cast<const float4*>(yrow)[t];
    float s = w.x * y.x + w.y * y.y + w.z * y.z + w.w * y.w;
    for (int m = 1; m < 64; m <<= 1) s += __shfl_xor(s, m);
    if (t == 0) h1[j] = elu_f(s + b1[j]);
}

__global__ __launch_bounds__(64) void k_mlp2(const float* __restrict__ w2, const float* __restrict__ b2,
                                             const float* __restrict__ h1, float* __restrict__ h2) {
    const int j = blockIdx.x, t = threadIdx.x;       // 256 blocks x 64 lanes, 8 elems/lane
    const float4* wr = reinterpret_cast<const float4*>(w2 + j * 512);
    const float4* hv = reinterpret_cast<const float4*>(h1);
    const float4 a = wr[t],      x = hv[t];
    const float4 b = wr[t + 64], y = hv[t + 64];
    float s = a.x * x.x + a.y * x.y + a.z * x.z + a.w * x.w
            + b.x * y.x + b.y * y.y + b.z * y.z + b.w * y.w;
    for (int m = 1; m < 64; m <<= 1) s += __shfl_xor(s, m);
    if (t == 0) h2[j] = elu_f(s + b2[j]);
}

__global__ __launch_bounds__(64) void k_mlp3(const float* __restrict__ w3, const float* __restrict__ b3,
                                             const float* __restrict__ h2, float* __restrict__ row) {
    const int j = blockIdx.x, t = threadIdx.x;       // 100 blocks x 64 lanes
    const float4 w = reinterpret_cast<const float4*>(w3 + j * 256)[t];
    const float4 h = reinterpret_cast<const float4*>(h2)[t];
    float s = w.x * h.x + w.y * h.y + w.z * h.z + w.w * h.w;
    for (int m = 1; m < 64; m <<= 1) s += __shfl_xor(s, m);
    if (t == 0) row[j] = s + b3[j];
}

// Broadcast the 100-float row to all 8192 output rows (25 float4 per row).
__global__ __launch_bounds__(256) void k_bcast(const float4* __restrict__ row4,
                                               float4* __restrict__ out4, int total4) {
    const int idx = blockIdx.x * blockDim.x + threadIdx.x;
    if (idx < total4) out4[idx] = row4[idx % 25];
}

extern "C" void kernel_launch(void* const* d_in, const int* in_sizes, int n_in,
                              void* d_out, int out_size, void* d_ws, size_t ws_size,
                              hipStream_t stream) {
    const float* const* in = (const float* const*)d_in;
    P1 p;
    p.norm_b    = in[2];
    p.in_proj_w = in[3];
    for (int dir = 0; dir < 3; ++dir) {
        const int base = 4 + dir * 7;
        p.conv_w[dir]   = in[base + 0];
        p.conv_b[dir]   = in[base + 1];
        p.xproj_w[dir]  = in[base + 2];
        p.dtproj_w[dir] = in[base + 3];
        p.dtproj_b[dir] = in[base + 4];
        p.A_log[dir]    = in[base + 5];
        p.Dskip[dir]    = in[base + 6];
    }
    p.out_proj_w = in[25];
    const float* w1 = in[26]; const float* b1 = in[27];
    const float* w2 = in[28]; const float* b2 = in[29];
    const float* w3 = in[30]; const float* b3 = in[31];

    float* ws   = (float*)d_ws;
    float* yrow = ws;            // 256 floats, 16B aligned
    float* h1   = ws + 256;      // 512 floats
    float* h2   = ws + 768;      // 256 floats
    float* row  = ws + 1024;     // 100 floats (offset 4096B, float4-aligned)
    p.yrow = yrow;

    k_row <<<1,   256, 0, stream>>>(p);
    k_mlp1<<<512, 64,  0, stream>>>(w1, b1, yrow, h1);
    k_mlp2<<<256, 64,  0, stream>>>(w2, b2, h1, h2);
    k_mlp3<<<100, 64,  0, stream>>>(w3, b3, h2, row);

    const int total4 = (8192 * 100) / 4;   // 204800
    k_bcast<<<(total4 + 255) / 256, 256, 0, stream>>>(
        (const float4*)row, (float4*)d_out, total4);
}